// Round 1
// baseline (759.288 us; speedup 1.0000x reference)
//
#include <hip/hip_runtime.h>

#define NN 50000
#define NE 800000
#define D  64
#define TILE 64
#define TPB 512
#define KTOT 192

// ---------------- CSR build ----------------

__global__ __launch_bounds__(256) void k_zero(int* __restrict__ p, int n) {
    int i = blockIdx.x * 256 + threadIdx.x;
    if (i < n) p[i] = 0;
}

__global__ __launch_bounds__(256) void k_count(const int* __restrict__ ei, int* __restrict__ deg) {
    int e = blockIdx.x * 256 + threadIdx.x;
    if (e < NE) atomicAdd(&deg[ei[NE + e]], 1);
}

// single-block exclusive scan over deg -> row_ptr (and cursor copy)
__global__ __launch_bounds__(1024) void k_scan(const int* __restrict__ deg,
                                               int* __restrict__ row_ptr,
                                               int* __restrict__ cursor) {
    __shared__ int part[1024];
    int tid = threadIdx.x;
    const int CH = (NN + 1023) / 1024;  // 49
    int b = tid * CH;
    int e = b + CH; if (e > NN) e = NN;
    if (b > NN) b = NN;
    int s = 0;
    for (int i = b; i < e; ++i) s += deg[i];
    part[tid] = s;
    __syncthreads();
    for (int off = 1; off < 1024; off <<= 1) {
        int v = (tid >= off) ? part[tid - off] : 0;
        __syncthreads();
        part[tid] += v;
        __syncthreads();
    }
    int base = (tid == 0) ? 0 : part[tid - 1];
    for (int i = b; i < e; ++i) { row_ptr[i] = base; cursor[i] = base; base += deg[i]; }
    if (tid == 1023) row_ptr[NN] = base;   // == NE
}

__global__ __launch_bounds__(256) void k_fill(const int* __restrict__ ei,
                                              int* __restrict__ cursor,
                                              int* __restrict__ colv) {
    int e = blockIdx.x * 256 + threadIdx.x;
    if (e < NE) {
        int d = ei[NE + e];
        int p = atomicAdd(&cursor[d], 1);
        colv[p] = ei[e];
    }
}

// ---------------- fused GIN conv: out = MLP(h + sum_{src in N(dst)} h[src]) ----------------

__global__ __launch_bounds__(TPB) void k_conv(
    const float* __restrict__ h,
    const int* __restrict__ row_ptr,
    const int* __restrict__ colv,
    const float* __restrict__ W1, const float* __restrict__ b1,
    const float* __restrict__ W2, const float* __restrict__ b2,
    float* __restrict__ out)
{
    __shared__ float sW1[D][D];
    __shared__ float sW2[D][D];
    __shared__ float sZ[TILE][D + 1];
    __shared__ float sH[TILE][D + 1];
    __shared__ float sB1[D], sB2[D];

    int tid = threadIdx.x;
    int node0 = blockIdx.x * TILE;

    for (int i = tid; i < D * D; i += TPB) {
        sW1[i >> 6][i & 63] = W1[i];
        sW2[i >> 6][i & 63] = W2[i];
    }
    if (tid < D) { sB1[tid] = b1[tid]; sB2[tid] = b2[tid]; }

    // aggregation: one wave per row, lane = feature
    int wave = tid >> 6, lane = tid & 63;
    for (int r = wave; r < TILE; r += (TPB / 64)) {
        int n = node0 + r;
        float a0 = 0.f, a1 = 0.f, a2 = 0.f, a3 = 0.f;
        if (n < NN) {
            a0 = h[n * D + lane];
            int e0 = row_ptr[n], e1 = row_ptr[n + 1];
            int e = e0;
            for (; e + 4 <= e1; e += 4) {
                int s0 = colv[e], s1 = colv[e + 1], s2 = colv[e + 2], s3 = colv[e + 3];
                a0 += h[s0 * D + lane];
                a1 += h[s1 * D + lane];
                a2 += h[s2 * D + lane];
                a3 += h[s3 * D + lane];
            }
            for (; e < e1; ++e) a1 += h[colv[e] * D + lane];
        }
        sZ[r][lane] = (a0 + a1) + (a2 + a3);
    }
    __syncthreads();

    // layer 1: sH = relu(sZ @ W1 + b1); each thread: 2 rows x 4 cols
    int tr = tid >> 4;   // 0..31 -> rows tr*2 + {0,1}
    int tc = tid & 15;   // cols tc + 16*c
    {
        float acc[2][4];
        #pragma unroll
        for (int i = 0; i < 2; ++i)
            #pragma unroll
            for (int c = 0; c < 4; ++c) acc[i][c] = sB1[tc + 16 * c];
        #pragma unroll 16
        for (int k = 0; k < D; ++k) {
            float z0 = sZ[tr * 2 + 0][k];
            float z1 = sZ[tr * 2 + 1][k];
            #pragma unroll
            for (int c = 0; c < 4; ++c) {
                float w = sW1[k][tc + 16 * c];
                acc[0][c] += z0 * w;
                acc[1][c] += z1 * w;
            }
        }
        #pragma unroll
        for (int i = 0; i < 2; ++i)
            #pragma unroll
            for (int c = 0; c < 4; ++c)
                sH[tr * 2 + i][tc + 16 * c] = fmaxf(acc[i][c], 0.f);
    }
    __syncthreads();

    // layer 2: out = sH @ W2 + b2
    {
        float acc[2][4];
        #pragma unroll
        for (int i = 0; i < 2; ++i)
            #pragma unroll
            for (int c = 0; c < 4; ++c) acc[i][c] = sB2[tc + 16 * c];
        #pragma unroll 16
        for (int k = 0; k < D; ++k) {
            float h0 = sH[tr * 2 + 0][k];
            float h1 = sH[tr * 2 + 1][k];
            #pragma unroll
            for (int c = 0; c < 4; ++c) {
                float w = sW2[k][tc + 16 * c];
                acc[0][c] += h0 * w;
                acc[1][c] += h1 * w;
            }
        }
        #pragma unroll
        for (int i = 0; i < 2; ++i) {
            int n = node0 + tr * 2 + i;
            if (n < NN) {
                #pragma unroll
                for (int c = 0; c < 4; ++c)
                    out[n * D + tc + 16 * c] = acc[i][c];
            }
        }
    }
}

// ---------------- final projection: out = [H0|H1|H2] @ Wo + bo ----------------

__global__ __launch_bounds__(TPB) void k_final(
    const float* __restrict__ H0, const float* __restrict__ H1,
    const float* __restrict__ H2,
    const float* __restrict__ Wo, const float* __restrict__ bo,
    float* __restrict__ out)
{
    __shared__ float sW[KTOT][D];          // 48 KB
    __shared__ float sZ[TILE][KTOT + 4];   // stride 196 words
    __shared__ float sB[D];

    int tid = threadIdx.x;
    int node0 = blockIdx.x * TILE;

    for (int i = tid; i < KTOT * D; i += TPB) sW[i >> 6][i & 63] = Wo[i];
    if (tid < D) sB[tid] = bo[tid];

    int wave = tid >> 6, lane = tid & 63;
    for (int r = wave; r < TILE; r += (TPB / 64)) {
        int n = node0 + r;
        float v0 = 0.f, v1 = 0.f, v2 = 0.f;
        if (n < NN) {
            v0 = H0[n * D + lane];
            v1 = H1[n * D + lane];
            v2 = H2[n * D + lane];
        }
        sZ[r][lane]       = v0;
        sZ[r][64 + lane]  = v1;
        sZ[r][128 + lane] = v2;
    }
    __syncthreads();

    int tr = tid >> 4, tc = tid & 15;
    float acc[2][4];
    #pragma unroll
    for (int i = 0; i < 2; ++i)
        #pragma unroll
        for (int c = 0; c < 4; ++c) acc[i][c] = sB[tc + 16 * c];
    #pragma unroll 16
    for (int k = 0; k < KTOT; ++k) {
        float z0 = sZ[tr * 2 + 0][k];
        float z1 = sZ[tr * 2 + 1][k];
        #pragma unroll
        for (int c = 0; c < 4; ++c) {
            float w = sW[k][tc + 16 * c];
            acc[0][c] += z0 * w;
            acc[1][c] += z1 * w;
        }
    }
    #pragma unroll
    for (int i = 0; i < 2; ++i) {
        int n = node0 + tr * 2 + i;
        if (n < NN) {
            #pragma unroll
            for (int c = 0; c < 4; ++c)
                out[n * D + tc + 16 * c] = acc[i][c];
        }
    }
}

// ---------------- launch ----------------

extern "C" void kernel_launch(void* const* d_in, const int* in_sizes, int n_in,
                              void* d_out, int out_size, void* d_ws, size_t ws_size,
                              hipStream_t stream) {
    const float* x    = (const float*)d_in[0];
    const int*   ei   = (const int*)d_in[1];   // [2, NE] int32 (JAX x64 disabled)
    const float* W1_0 = (const float*)d_in[2];
    const float* b1_0 = (const float*)d_in[3];
    const float* W2_0 = (const float*)d_in[4];
    const float* b2_0 = (const float*)d_in[5];
    const float* W1_1 = (const float*)d_in[6];
    const float* b1_1 = (const float*)d_in[7];
    const float* W2_1 = (const float*)d_in[8];
    const float* b2_1 = (const float*)d_in[9];
    const float* W1_2 = (const float*)d_in[10];
    const float* b1_2 = (const float*)d_in[11];
    const float* W2_2 = (const float*)d_in[12];
    const float* b2_2 = (const float*)d_in[13];
    const float* Wo   = (const float*)d_in[14];
    const float* bo   = (const float*)d_in[15];
    float* out = (float*)d_out;

    char* ws = (char*)d_ws;
    int* deg     = (int*)(ws + 0);         // 50000 ints
    int* cursor  = (int*)(ws + 200704);    // 50000 ints
    int* row_ptr = (int*)(ws + 401408);    // 50001 ints
    int* colv    = (int*)(ws + 602112);    // 800000 ints
    float* fbase = (float*)(ws + 3802112);
    float* H0 = fbase;                     // 3.2M floats each
    float* H1 = fbase + 3200000;
    float* H2 = fbase + 6400000;
    float* tA = fbase + 9600000;

    // CSR build
    k_zero<<<(NN + 255) / 256, 256, 0, stream>>>(deg, NN);
    k_count<<<(NE + 255) / 256, 256, 0, stream>>>(ei, deg);
    k_scan<<<1, 1024, 0, stream>>>(deg, row_ptr, cursor);
    k_fill<<<(NE + 255) / 256, 256, 0, stream>>>(ei, cursor, colv);

    int nb = (NN + TILE - 1) / TILE;  // 782

    // hop-3 chain (params 2), using d_out as intermediate scratch
    k_conv<<<nb, TPB, 0, stream>>>(x,   row_ptr, colv, W1_2, b1_2, W2_2, b2_2, tA);
    k_conv<<<nb, TPB, 0, stream>>>(tA,  row_ptr, colv, W1_2, b1_2, W2_2, b2_2, out);
    k_conv<<<nb, TPB, 0, stream>>>(out, row_ptr, colv, W1_2, b1_2, W2_2, b2_2, H2);

    // hop-2 chain (params 1)
    k_conv<<<nb, TPB, 0, stream>>>(x,  row_ptr, colv, W1_1, b1_1, W2_1, b2_1, tA);
    k_conv<<<nb, TPB, 0, stream>>>(tA, row_ptr, colv, W1_1, b1_1, W2_1, b2_1, H1);

    // hop-1 (params 0)
    k_conv<<<nb, TPB, 0, stream>>>(x, row_ptr, colv, W1_0, b1_0, W2_0, b2_0, H0);

    // final projection
    k_final<<<nb, TPB, 0, stream>>>(H0, H1, H2, Wo, bo, out);
}

// Round 2
// 468.057 us; speedup vs baseline: 1.6222x; 1.6222x over previous
//
#include <hip/hip_runtime.h>

#define NN 50000
#define NE 800000
#define D  64
#define TILE 64
#define TPB 512
#define KTOT 192
#define NBLK 196   // ceil(NN/256)

// ---------------- CSR build ----------------

__global__ __launch_bounds__(256) void k_zero(int* __restrict__ p, int n) {
    int i = blockIdx.x * 256 + threadIdx.x;
    if (i < n) p[i] = 0;
}

__global__ __launch_bounds__(256) void k_count(const int* __restrict__ ei, int* __restrict__ deg) {
    int e = blockIdx.x * 256 + threadIdx.x;
    if (e < NE) atomicAdd(&deg[ei[NE + e]], 1);
}

// phase A: per-block partial sums of deg
__global__ __launch_bounds__(256) void k_bsum(const int* __restrict__ deg, int* __restrict__ bsum) {
    __shared__ int s[256];
    int t = threadIdx.x;
    int i = blockIdx.x * 256 + t;
    s[t] = (i < NN) ? deg[i] : 0;
    __syncthreads();
    for (int off = 128; off > 0; off >>= 1) {
        if (t < off) s[t] += s[t + off];
        __syncthreads();
    }
    if (t == 0) bsum[blockIdx.x] = s[0];
}

// phase B: exclusive scan of block sums
__global__ __launch_bounds__(256) void k_boff(const int* __restrict__ bsum,
                                              int* __restrict__ boff,
                                              int* __restrict__ row_ptr) {
    __shared__ int s[256];
    int t = threadIdx.x;
    int v = (t < NBLK) ? bsum[t] : 0;
    s[t] = v;
    __syncthreads();
    for (int off = 1; off < 256; off <<= 1) {
        int u = (t >= off) ? s[t - off] : 0;
        __syncthreads();
        s[t] += u;
        __syncthreads();
    }
    boff[t] = s[t] - v;
    if (t == 0) row_ptr[NN] = NE;
}

// phase C: per-block exclusive scan + offset -> row_ptr, cursor
__global__ __launch_bounds__(256) void k_scan2(const int* __restrict__ deg,
                                               const int* __restrict__ boff,
                                               int* __restrict__ row_ptr,
                                               int* __restrict__ cursor) {
    __shared__ int s[256];
    int t = threadIdx.x;
    int i = blockIdx.x * 256 + t;
    int v = (i < NN) ? deg[i] : 0;
    s[t] = v;
    __syncthreads();
    for (int off = 1; off < 256; off <<= 1) {
        int u = (t >= off) ? s[t - off] : 0;
        __syncthreads();
        s[t] += u;
        __syncthreads();
    }
    int excl = s[t] - v + boff[blockIdx.x];
    if (i < NN) { row_ptr[i] = excl; cursor[i] = excl; }
}

__global__ __launch_bounds__(256) void k_fill(const int* __restrict__ ei,
                                              int* __restrict__ cursor,
                                              int* __restrict__ colv) {
    int e = blockIdx.x * 256 + threadIdx.x;
    if (e < NE) {
        int d = ei[NE + e];
        int p = atomicAdd(&cursor[d], 1);
        colv[p] = ei[e];
    }
}

// ---------------- fused GIN conv: out = MLP(h + sum_{src in N(dst)} h[src]) ----------------
// Gather: one wave per dst row; 4 groups of 16 lanes each handle one edge
// (float4 per lane = 16 B), 2-way unrolled; shfl-xor combine across groups.

__global__ __launch_bounds__(TPB) void k_conv(
    const float4* __restrict__ h4,
    const int* __restrict__ row_ptr,
    const int* __restrict__ colv,
    const float* __restrict__ W1, const float* __restrict__ b1,
    const float* __restrict__ W2, const float* __restrict__ b2,
    float4* __restrict__ out4)
{
    __shared__ float sW1[D][D];
    __shared__ float sW2[D][D];
    __shared__ float4 sZ4[TILE][17];   // row stride 272 B
    __shared__ float sB1[D], sB2[D];

    int tid = threadIdx.x;
    int node0 = blockIdx.x * TILE;

    {
        const float4* w14 = (const float4*)W1;
        const float4* w24 = (const float4*)W2;
        float4* s14 = (float4*)sW1;
        float4* s24 = (float4*)sW2;
        for (int i = tid; i < D * D / 4; i += TPB) { s14[i] = w14[i]; s24[i] = w24[i]; }
        if (tid < D) { sB1[tid] = b1[tid]; sB2[tid] = b2[tid]; }
    }

    int wave = tid >> 6, lane = tid & 63;
    int g = lane >> 4, q = lane & 15;

    for (int r = wave; r < TILE; r += (TPB / 64)) {
        int n = node0 + r;                 // uniform across the wave
        float4 a0 = make_float4(0.f, 0.f, 0.f, 0.f);
        float4 a1 = make_float4(0.f, 0.f, 0.f, 0.f);
        if (n < NN) {
            if (g == 0) a0 = h4[n * 16 + q];          // self term
            int e1 = row_ptr[n + 1];
            int e  = row_ptr[n] + g;
            for (; e + 4 < e1; e += 8) {
                int s0 = colv[e], s1 = colv[e + 4];
                float4 v0 = h4[s0 * 16 + q];
                float4 v1 = h4[s1 * 16 + q];
                a0.x += v0.x; a0.y += v0.y; a0.z += v0.z; a0.w += v0.w;
                a1.x += v1.x; a1.y += v1.y; a1.z += v1.z; a1.w += v1.w;
            }
            if (e < e1) {
                float4 v0 = h4[colv[e] * 16 + q];
                a0.x += v0.x; a0.y += v0.y; a0.z += v0.z; a0.w += v0.w;
            }
            a0.x += a1.x; a0.y += a1.y; a0.z += a1.z; a0.w += a1.w;
        }
        // combine the 4 groups (wave-uniform control; all lanes participate)
        a0.x += __shfl_xor(a0.x, 16); a0.y += __shfl_xor(a0.y, 16);
        a0.z += __shfl_xor(a0.z, 16); a0.w += __shfl_xor(a0.w, 16);
        a0.x += __shfl_xor(a0.x, 32); a0.y += __shfl_xor(a0.y, 32);
        a0.z += __shfl_xor(a0.z, 32); a0.w += __shfl_xor(a0.w, 32);
        if (g == 0) sZ4[r][q] = a0;
    }
    __syncthreads();

    // MLP: thread (tr,tc) owns rows tr*2+{0,1}, cols tc*4+{0..3}.
    // Row r is read AND written only by its own 16-thread group (one wave) ->
    // same-wave LDS program order makes the in-place writeback safe, no barrier.
    int tr = tid >> 4, tc = tid & 15;
    float* zr0 = (float*)&sZ4[tr * 2 + 0][0];
    float* zr1 = (float*)&sZ4[tr * 2 + 1][0];

    float acc[2][4];
    #pragma unroll
    for (int c = 0; c < 4; ++c) { acc[0][c] = sB1[tc * 4 + c]; acc[1][c] = sB1[tc * 4 + c]; }
    #pragma unroll 16
    for (int k = 0; k < D; ++k) {
        float z0 = zr0[k], z1 = zr1[k];
        #pragma unroll
        for (int c = 0; c < 4; ++c) {
            float w = sW1[k][tc * 4 + c];
            acc[0][c] += z0 * w;
            acc[1][c] += z1 * w;
        }
    }
    {
        float4 h0, h1;
        h0.x = fmaxf(acc[0][0], 0.f); h0.y = fmaxf(acc[0][1], 0.f);
        h0.z = fmaxf(acc[0][2], 0.f); h0.w = fmaxf(acc[0][3], 0.f);
        h1.x = fmaxf(acc[1][0], 0.f); h1.y = fmaxf(acc[1][1], 0.f);
        h1.z = fmaxf(acc[1][2], 0.f); h1.w = fmaxf(acc[1][3], 0.f);
        *(float4*)&zr0[tc * 4] = h0;
        *(float4*)&zr1[tc * 4] = h1;
    }
    #pragma unroll
    for (int c = 0; c < 4; ++c) { acc[0][c] = sB2[tc * 4 + c]; acc[1][c] = sB2[tc * 4 + c]; }
    #pragma unroll 16
    for (int k = 0; k < D; ++k) {
        float z0 = zr0[k], z1 = zr1[k];
        #pragma unroll
        for (int c = 0; c < 4; ++c) {
            float w = sW2[k][tc * 4 + c];
            acc[0][c] += z0 * w;
            acc[1][c] += z1 * w;
        }
    }
    #pragma unroll
    for (int i = 0; i < 2; ++i) {
        int n = node0 + tr * 2 + i;
        if (n < NN) {
            float4 o;
            o.x = acc[i][0]; o.y = acc[i][1]; o.z = acc[i][2]; o.w = acc[i][3];
            out4[n * 16 + tc] = o;
        }
    }
}

// ---------------- final projection: out = [H0|H1|H2] @ Wo + bo ----------------

__global__ __launch_bounds__(TPB) void k_final(
    const float4* __restrict__ H0, const float4* __restrict__ H1,
    const float4* __restrict__ H2,
    const float* __restrict__ Wo, const float* __restrict__ bo,
    float4* __restrict__ out4)
{
    __shared__ float4 sW4[KTOT * 16];      // 48 KB, alias float [k*64+col]
    __shared__ float4 sZ4[TILE][49];       // row stride 784 B (196 floats)
    __shared__ float sB[D];

    int tid = threadIdx.x;
    int node0 = blockIdx.x * TILE;

    {
        const float4* w4 = (const float4*)Wo;
        for (int i = tid; i < KTOT * 16; i += TPB) sW4[i] = w4[i];
        if (tid < D) sB[tid] = bo[tid];
    }

    int wave = tid >> 6, lane = tid & 63;
    int part = lane >> 4, q = lane & 15;
    for (int r = wave; r < TILE; r += (TPB / 64)) {
        int n = node0 + r;
        if (n < NN && part < 3) {
            const float4* hp = (part == 0) ? H0 : (part == 1) ? H1 : H2;
            sZ4[r][part * 16 + q] = hp[n * 16 + q];
        } else if (part < 3) {
            sZ4[r][part * 16 + q] = make_float4(0.f, 0.f, 0.f, 0.f);
        }
    }
    __syncthreads();

    const float* sW = (const float*)sW4;
    int tr = tid >> 4, tc = tid & 15;
    const float* zr0 = (const float*)&sZ4[tr * 2 + 0][0];
    const float* zr1 = (const float*)&sZ4[tr * 2 + 1][0];

    float acc[2][4];
    #pragma unroll
    for (int c = 0; c < 4; ++c) { acc[0][c] = sB[tc * 4 + c]; acc[1][c] = sB[tc * 4 + c]; }
    #pragma unroll 8
    for (int k = 0; k < KTOT; ++k) {
        float z0 = zr0[k], z1 = zr1[k];
        #pragma unroll
        for (int c = 0; c < 4; ++c) {
            float w = sW[k * 64 + tc * 4 + c];
            acc[0][c] += z0 * w;
            acc[1][c] += z1 * w;
        }
    }
    #pragma unroll
    for (int i = 0; i < 2; ++i) {
        int n = node0 + tr * 2 + i;
        if (n < NN) {
            float4 o;
            o.x = acc[i][0]; o.y = acc[i][1]; o.z = acc[i][2]; o.w = acc[i][3];
            out4[n * 16 + tc] = o;
        }
    }
}

// ---------------- launch ----------------

extern "C" void kernel_launch(void* const* d_in, const int* in_sizes, int n_in,
                              void* d_out, int out_size, void* d_ws, size_t ws_size,
                              hipStream_t stream) {
    const float* x    = (const float*)d_in[0];
    const int*   ei   = (const int*)d_in[1];   // [2, NE] int32
    const float* W1_0 = (const float*)d_in[2];
    const float* b1_0 = (const float*)d_in[3];
    const float* W2_0 = (const float*)d_in[4];
    const float* b2_0 = (const float*)d_in[5];
    const float* W1_1 = (const float*)d_in[6];
    const float* b1_1 = (const float*)d_in[7];
    const float* W2_1 = (const float*)d_in[8];
    const float* b2_1 = (const float*)d_in[9];
    const float* W1_2 = (const float*)d_in[10];
    const float* b1_2 = (const float*)d_in[11];
    const float* W2_2 = (const float*)d_in[12];
    const float* b2_2 = (const float*)d_in[13];
    const float* Wo   = (const float*)d_in[14];
    const float* bo   = (const float*)d_in[15];
    float4* out = (float4*)d_out;

    char* ws = (char*)d_ws;
    int* deg     = (int*)(ws + 0);          // 50000 ints
    int* cursor  = (int*)(ws + 200704);     // 50000 ints
    int* row_ptr = (int*)(ws + 401408);     // 50001 ints
    int* colv    = (int*)(ws + 602112);     // 800000 ints
    int* bsum    = (int*)(ws + 3802112);    // 256 ints
    int* boff    = (int*)(ws + 3803136);    // 256 ints
    float* fbase = (float*)(ws + 3804160);  // 16B-aligned
    float4* H0 = (float4*)(fbase);
    float4* H1 = (float4*)(fbase + 3200000);
    float4* H2 = (float4*)(fbase + 6400000);
    float4* tA = (float4*)(fbase + 9600000);
    const float4* x4 = (const float4*)x;

    // CSR build
    k_zero <<<NBLK, 256, 0, stream>>>(deg, NN);
    k_count<<<(NE + 255) / 256, 256, 0, stream>>>(ei, deg);
    k_bsum <<<NBLK, 256, 0, stream>>>(deg, bsum);
    k_boff <<<1, 256, 0, stream>>>(bsum, boff, row_ptr);
    k_scan2<<<NBLK, 256, 0, stream>>>(deg, boff, row_ptr, cursor);
    k_fill <<<(NE + 255) / 256, 256, 0, stream>>>(ei, cursor, colv);

    int nb = (NN + TILE - 1) / TILE;  // 782

    // hop-3 chain (params 2), d_out as one intermediate
    k_conv<<<nb, TPB, 0, stream>>>(x4,            row_ptr, colv, W1_2, b1_2, W2_2, b2_2, tA);
    k_conv<<<nb, TPB, 0, stream>>>((const float4*)tA,  row_ptr, colv, W1_2, b1_2, W2_2, b2_2, out);
    k_conv<<<nb, TPB, 0, stream>>>((const float4*)out, row_ptr, colv, W1_2, b1_2, W2_2, b2_2, H2);

    // hop-2 chain (params 1)
    k_conv<<<nb, TPB, 0, stream>>>(x4,               row_ptr, colv, W1_1, b1_1, W2_1, b2_1, tA);
    k_conv<<<nb, TPB, 0, stream>>>((const float4*)tA, row_ptr, colv, W1_1, b1_1, W2_1, b2_1, H1);

    // hop-1 (params 0)
    k_conv<<<nb, TPB, 0, stream>>>(x4, row_ptr, colv, W1_0, b1_0, W2_0, b2_0, H0);

    // final projection
    k_final<<<nb, TPB, 0, stream>>>((const float4*)H0, (const float4*)H1, (const float4*)H2,
                                    Wo, bo, out);
}

// Round 3
// 397.543 us; speedup vs baseline: 1.9100x; 1.1774x over previous
//
#include <hip/hip_runtime.h>

#define NN 50000
#define NE 800000
#define D  64
#define TILE 64
#define TPB 512
#define KTOT 192
#define NBLK 196   // ceil(NN/256)

// ---------------- CSR build ----------------

__global__ __launch_bounds__(256) void k_zero(int* __restrict__ p, int n) {
    int i = blockIdx.x * 256 + threadIdx.x;
    if (i < n) p[i] = 0;
}

__global__ __launch_bounds__(256) void k_count(const int* __restrict__ ei, int* __restrict__ deg) {
    int e = blockIdx.x * 256 + threadIdx.x;
    if (e < NE) atomicAdd(&deg[ei[NE + e]], 1);
}

__global__ __launch_bounds__(256) void k_bsum(const int* __restrict__ deg, int* __restrict__ bsum) {
    __shared__ int s[256];
    int t = threadIdx.x;
    int i = blockIdx.x * 256 + t;
    s[t] = (i < NN) ? deg[i] : 0;
    __syncthreads();
    for (int off = 128; off > 0; off >>= 1) {
        if (t < off) s[t] += s[t + off];
        __syncthreads();
    }
    if (t == 0) bsum[blockIdx.x] = s[0];
}

__global__ __launch_bounds__(256) void k_boff(const int* __restrict__ bsum,
                                              int* __restrict__ boff,
                                              int* __restrict__ row_ptr) {
    __shared__ int s[256];
    int t = threadIdx.x;
    int v = (t < NBLK) ? bsum[t] : 0;
    s[t] = v;
    __syncthreads();
    for (int off = 1; off < 256; off <<= 1) {
        int u = (t >= off) ? s[t - off] : 0;
        __syncthreads();
        s[t] += u;
        __syncthreads();
    }
    boff[t] = s[t] - v;
    if (t == 0) row_ptr[NN] = NE;
}

__global__ __launch_bounds__(256) void k_scan2(const int* __restrict__ deg,
                                               const int* __restrict__ boff,
                                               int* __restrict__ row_ptr,
                                               int* __restrict__ cursor) {
    __shared__ int s[256];
    int t = threadIdx.x;
    int i = blockIdx.x * 256 + t;
    int v = (i < NN) ? deg[i] : 0;
    s[t] = v;
    __syncthreads();
    for (int off = 1; off < 256; off <<= 1) {
        int u = (t >= off) ? s[t - off] : 0;
        __syncthreads();
        s[t] += u;
        __syncthreads();
    }
    int excl = s[t] - v + boff[blockIdx.x];
    if (i < NN) { row_ptr[i] = excl; cursor[i] = excl; }
}

__global__ __launch_bounds__(256) void k_fill(const int* __restrict__ ei,
                                              int* __restrict__ cursor,
                                              int* __restrict__ colv) {
    int e = blockIdx.x * 256 + threadIdx.x;
    if (e < NE) {
        int d = ei[NE + e];
        int p = atomicAdd(&cursor[d], 1);
        colv[p] = ei[e];
    }
}

// ---------------- gather helper (device inline) ----------------
// One wave per dst row; 4 groups of 16 lanes; each group walks edges with
// stride 4, unroll 4 (4 independent colv->h4 load chains in flight).

__device__ __forceinline__ float4 gather_row(const float4* __restrict__ h4,
                                             const int* __restrict__ row_ptr,
                                             const int* __restrict__ colv,
                                             int n, int g, int q) {
    float4 a0 = make_float4(0.f, 0.f, 0.f, 0.f);
    float4 a1 = make_float4(0.f, 0.f, 0.f, 0.f);
    float4 a2 = make_float4(0.f, 0.f, 0.f, 0.f);
    float4 a3 = make_float4(0.f, 0.f, 0.f, 0.f);
    if (n >= 0) {
        if (g == 0) a0 = h4[n * 16 + q];           // self term
        int e1 = row_ptr[n + 1];
        int e  = row_ptr[n] + g;
        for (; e + 12 < e1; e += 16) {
            int s0 = colv[e], s1 = colv[e + 4], s2 = colv[e + 8], s3 = colv[e + 12];
            float4 v0 = h4[s0 * 16 + q];
            float4 v1 = h4[s1 * 16 + q];
            float4 v2 = h4[s2 * 16 + q];
            float4 v3 = h4[s3 * 16 + q];
            a0.x += v0.x; a0.y += v0.y; a0.z += v0.z; a0.w += v0.w;
            a1.x += v1.x; a1.y += v1.y; a1.z += v1.z; a1.w += v1.w;
            a2.x += v2.x; a2.y += v2.y; a2.z += v2.z; a2.w += v2.w;
            a3.x += v3.x; a3.y += v3.y; a3.z += v3.z; a3.w += v3.w;
        }
        for (; e < e1; e += 4) {
            float4 v = h4[colv[e] * 16 + q];
            a1.x += v.x; a1.y += v.y; a1.z += v.z; a1.w += v.w;
        }
        a0.x += a1.x + a2.x + a3.x;
        a0.y += a1.y + a2.y + a3.y;
        a0.z += a1.z + a2.z + a3.z;
        a0.w += a1.w + a2.w + a3.w;
    }
    // combine the 4 groups (wave-uniform control)
    a0.x += __shfl_xor(a0.x, 16); a0.y += __shfl_xor(a0.y, 16);
    a0.z += __shfl_xor(a0.z, 16); a0.w += __shfl_xor(a0.w, 16);
    a0.x += __shfl_xor(a0.x, 32); a0.y += __shfl_xor(a0.y, 32);
    a0.z += __shfl_xor(a0.z, 32); a0.w += __shfl_xor(a0.w, 32);
    return a0;
}

// ---------------- fused GIN conv: out = MLP(h + sum h[src]) ----------------

__global__ __launch_bounds__(TPB) void k_conv(
    const float4* __restrict__ h4,
    const int* __restrict__ row_ptr,
    const int* __restrict__ colv,
    const float* __restrict__ W1, const float* __restrict__ b1,
    const float* __restrict__ W2, const float* __restrict__ b2,
    float4* __restrict__ out4)
{
    __shared__ float sW1[D][D];
    __shared__ float sW2[D][D];
    __shared__ float4 sZ4[TILE][17];
    __shared__ float sB1[D], sB2[D];

    int tid = threadIdx.x;
    int node0 = blockIdx.x * TILE;

    {
        const float4* w14 = (const float4*)W1;
        const float4* w24 = (const float4*)W2;
        float4* s14 = (float4*)sW1;
        float4* s24 = (float4*)sW2;
        for (int i = tid; i < D * D / 4; i += TPB) { s14[i] = w14[i]; s24[i] = w24[i]; }
        if (tid < D) { sB1[tid] = b1[tid]; sB2[tid] = b2[tid]; }
    }

    int wave = tid >> 6, lane = tid & 63;
    int g = lane >> 4, q = lane & 15;

    for (int r = wave; r < TILE; r += (TPB / 64)) {
        int n = node0 + r;
        float4 a = gather_row(h4, row_ptr, colv, (n < NN) ? n : -1, g, q);
        if (g == 0) sZ4[r][q] = a;
    }
    __syncthreads();

    // MLP with same-wave in-place writeback (row owned by one 16-thread group)
    int tr = tid >> 4, tc = tid & 15;
    float* zr0 = (float*)&sZ4[tr * 2 + 0][0];
    float* zr1 = (float*)&sZ4[tr * 2 + 1][0];

    float acc[2][4];
    #pragma unroll
    for (int c = 0; c < 4; ++c) { acc[0][c] = sB1[tc * 4 + c]; acc[1][c] = sB1[tc * 4 + c]; }
    #pragma unroll 16
    for (int k = 0; k < D; ++k) {
        float z0 = zr0[k], z1 = zr1[k];
        #pragma unroll
        for (int c = 0; c < 4; ++c) {
            float w = sW1[k][tc * 4 + c];
            acc[0][c] += z0 * w;
            acc[1][c] += z1 * w;
        }
    }
    {
        float4 h0, h1;
        h0.x = fmaxf(acc[0][0], 0.f); h0.y = fmaxf(acc[0][1], 0.f);
        h0.z = fmaxf(acc[0][2], 0.f); h0.w = fmaxf(acc[0][3], 0.f);
        h1.x = fmaxf(acc[1][0], 0.f); h1.y = fmaxf(acc[1][1], 0.f);
        h1.z = fmaxf(acc[1][2], 0.f); h1.w = fmaxf(acc[1][3], 0.f);
        *(float4*)&zr0[tc * 4] = h0;
        *(float4*)&zr1[tc * 4] = h1;
    }
    #pragma unroll
    for (int c = 0; c < 4; ++c) { acc[0][c] = sB2[tc * 4 + c]; acc[1][c] = sB2[tc * 4 + c]; }
    #pragma unroll 16
    for (int k = 0; k < D; ++k) {
        float z0 = zr0[k], z1 = zr1[k];
        #pragma unroll
        for (int c = 0; c < 4; ++c) {
            float w = sW2[k][tc * 4 + c];
            acc[0][c] += z0 * w;
            acc[1][c] += z1 * w;
        }
    }
    #pragma unroll
    for (int i = 0; i < 2; ++i) {
        int n = node0 + tr * 2 + i;
        if (n < NN) {
            float4 o;
            o.x = acc[i][0]; o.y = acc[i][1]; o.z = acc[i][2]; o.w = acc[i][3];
            out4[n * 16 + tc] = o;
        }
    }
}

// ---------------- one gather of x, three MLPs (params 0/1/2) ----------------

__global__ __launch_bounds__(TPB) void k_aggmlp3(
    const float4* __restrict__ h4,
    const int* __restrict__ row_ptr,
    const int* __restrict__ colv,
    const float* __restrict__ W1a, const float* __restrict__ b1a,
    const float* __restrict__ W2a, const float* __restrict__ b2a,
    const float* __restrict__ W1b, const float* __restrict__ b1b,
    const float* __restrict__ W2b, const float* __restrict__ b2b,
    const float* __restrict__ W1c, const float* __restrict__ b1c,
    const float* __restrict__ W2c, const float* __restrict__ b2c,
    float4* __restrict__ outA, float4* __restrict__ outB, float4* __restrict__ outC)
{
    __shared__ float sW[D][D];          // 16 KB, reloaded per layer
    __shared__ float4 sZ4[TILE][17];    // z = x + agg (preserved)
    __shared__ float4 sH4[TILE][17];    // layer-1 output
    __shared__ float sB[D];

    int tid = threadIdx.x;
    int node0 = blockIdx.x * TILE;

    int wave = tid >> 6, lane = tid & 63;
    int g = lane >> 4, q = lane & 63 & 15;

    for (int r = wave; r < TILE; r += (TPB / 64)) {
        int n = node0 + r;
        float4 a = gather_row(h4, row_ptr, colv, (n < NN) ? n : -1, g, q);
        if (g == 0) sZ4[r][q] = a;
    }

    int tr = tid >> 4, tc = tid & 15;
    float* zr0 = (float*)&sZ4[tr * 2 + 0][0];
    float* zr1 = (float*)&sZ4[tr * 2 + 1][0];
    float* hr0 = (float*)&sH4[tr * 2 + 0][0];
    float* hr1 = (float*)&sH4[tr * 2 + 1][0];

    #pragma unroll 1
    for (int m = 0; m < 3; ++m) {
        const float* W1 = (m == 0) ? W1a : (m == 1) ? W1b : W1c;
        const float* B1 = (m == 0) ? b1a : (m == 1) ? b1b : b1c;
        const float* W2 = (m == 0) ? W2a : (m == 1) ? W2b : W2c;
        const float* B2 = (m == 0) ? b2a : (m == 1) ? b2b : b2c;
        float4* out4 = (m == 0) ? outA : (m == 1) ? outB : outC;

        // load W1, b1 (first iteration's sync also covers the gather)
        {
            const float4* w4 = (const float4*)W1;
            float4* s4 = (float4*)sW;
            for (int i = tid; i < D * D / 4; i += TPB) s4[i] = w4[i];
            if (tid < D) sB[tid] = B1[tid];
        }
        __syncthreads();

        float acc[2][4];
        #pragma unroll
        for (int c = 0; c < 4; ++c) { acc[0][c] = sB[tc * 4 + c]; acc[1][c] = sB[tc * 4 + c]; }
        #pragma unroll 16
        for (int k = 0; k < D; ++k) {
            float z0 = zr0[k], z1 = zr1[k];
            #pragma unroll
            for (int c = 0; c < 4; ++c) {
                float w = sW[k][tc * 4 + c];
                acc[0][c] += z0 * w;
                acc[1][c] += z1 * w;
            }
        }
        {
            float4 h0, h1;
            h0.x = fmaxf(acc[0][0], 0.f); h0.y = fmaxf(acc[0][1], 0.f);
            h0.z = fmaxf(acc[0][2], 0.f); h0.w = fmaxf(acc[0][3], 0.f);
            h1.x = fmaxf(acc[1][0], 0.f); h1.y = fmaxf(acc[1][1], 0.f);
            h1.z = fmaxf(acc[1][2], 0.f); h1.w = fmaxf(acc[1][3], 0.f);
            *(float4*)&hr0[tc * 4] = h0;
            *(float4*)&hr1[tc * 4] = h1;
        }
        __syncthreads();

        // load W2, b2
        {
            const float4* w4 = (const float4*)W2;
            float4* s4 = (float4*)sW;
            for (int i = tid; i < D * D / 4; i += TPB) s4[i] = w4[i];
            if (tid < D) sB[tid] = B2[tid];
        }
        __syncthreads();

        #pragma unroll
        for (int c = 0; c < 4; ++c) { acc[0][c] = sB[tc * 4 + c]; acc[1][c] = sB[tc * 4 + c]; }
        #pragma unroll 16
        for (int k = 0; k < D; ++k) {
            float h0 = hr0[k], h1 = hr1[k];
            #pragma unroll
            for (int c = 0; c < 4; ++c) {
                float w = sW[k][tc * 4 + c];
                acc[0][c] += h0 * w;
                acc[1][c] += h1 * w;
            }
        }
        #pragma unroll
        for (int i = 0; i < 2; ++i) {
            int n = node0 + tr * 2 + i;
            if (n < NN) {
                float4 o;
                o.x = acc[i][0]; o.y = acc[i][1]; o.z = acc[i][2]; o.w = acc[i][3];
                out4[n * 16 + tc] = o;
            }
        }
        __syncthreads();   // protect sW/sB before next MLP's load
    }
}

// ---------------- final projection: out = [H0|H1|H2] @ Wo + bo ----------------

__global__ __launch_bounds__(TPB) void k_final(
    const float4* __restrict__ H0, const float4* __restrict__ H1,
    const float4* __restrict__ H2,
    const float* __restrict__ Wo, const float* __restrict__ bo,
    float4* __restrict__ out4)
{
    __shared__ float4 sW4[KTOT * 16];      // 48 KB
    __shared__ float4 sZ4[TILE][49];       // 196-float row stride
    __shared__ float sB[D];

    int tid = threadIdx.x;
    int node0 = blockIdx.x * TILE;

    {
        const float4* w4 = (const float4*)Wo;
        for (int i = tid; i < KTOT * 16; i += TPB) sW4[i] = w4[i];
        if (tid < D) sB[tid] = bo[tid];
    }

    int wave = tid >> 6, lane = tid & 63;
    int part = lane >> 4, q = lane & 15;
    for (int r = wave; r < TILE; r += (TPB / 64)) {
        int n = node0 + r;
        if (part < 3) {
            float4 v = make_float4(0.f, 0.f, 0.f, 0.f);
            if (n < NN) {
                const float4* hp = (part == 0) ? H0 : (part == 1) ? H1 : H2;
                v = hp[n * 16 + q];
            }
            sZ4[r][part * 16 + q] = v;
        }
    }
    __syncthreads();

    const float* sW = (const float*)sW4;
    int tr = tid >> 4, tc = tid & 15;
    const float* zr0 = (const float*)&sZ4[tr * 2 + 0][0];
    const float* zr1 = (const float*)&sZ4[tr * 2 + 1][0];

    float acc[2][4];
    #pragma unroll
    for (int c = 0; c < 4; ++c) { acc[0][c] = sB[tc * 4 + c]; acc[1][c] = sB[tc * 4 + c]; }
    #pragma unroll 8
    for (int k = 0; k < KTOT; ++k) {
        float z0 = zr0[k], z1 = zr1[k];
        #pragma unroll
        for (int c = 0; c < 4; ++c) {
            float w = sW[k * 64 + tc * 4 + c];
            acc[0][c] += z0 * w;
            acc[1][c] += z1 * w;
        }
    }
    #pragma unroll
    for (int i = 0; i < 2; ++i) {
        int n = node0 + tr * 2 + i;
        if (n < NN) {
            float4 o;
            o.x = acc[i][0]; o.y = acc[i][1]; o.z = acc[i][2]; o.w = acc[i][3];
            out4[n * 16 + tc] = o;
        }
    }
}

// ---------------- launch ----------------

extern "C" void kernel_launch(void* const* d_in, const int* in_sizes, int n_in,
                              void* d_out, int out_size, void* d_ws, size_t ws_size,
                              hipStream_t stream) {
    const float* x    = (const float*)d_in[0];
    const int*   ei   = (const int*)d_in[1];   // [2, NE] int32
    const float* W1_0 = (const float*)d_in[2];
    const float* b1_0 = (const float*)d_in[3];
    const float* W2_0 = (const float*)d_in[4];
    const float* b2_0 = (const float*)d_in[5];
    const float* W1_1 = (const float*)d_in[6];
    const float* b1_1 = (const float*)d_in[7];
    const float* W2_1 = (const float*)d_in[8];
    const float* b2_1 = (const float*)d_in[9];
    const float* W1_2 = (const float*)d_in[10];
    const float* b1_2 = (const float*)d_in[11];
    const float* W2_2 = (const float*)d_in[12];
    const float* b2_2 = (const float*)d_in[13];
    const float* Wo   = (const float*)d_in[14];
    const float* bo   = (const float*)d_in[15];
    float4* out = (float4*)d_out;

    char* ws = (char*)d_ws;
    int* deg     = (int*)(ws + 0);
    int* cursor  = (int*)(ws + 200704);
    int* row_ptr = (int*)(ws + 401408);
    int* colv    = (int*)(ws + 602112);
    int* bsum    = (int*)(ws + 3802112);
    int* boff    = (int*)(ws + 3803136);
    float* fbase = (float*)(ws + 3804160);
    float4* H0 = (float4*)(fbase);
    float4* H1 = (float4*)(fbase + 3200000);
    float4* H2 = (float4*)(fbase + 6400000);
    float4* tA = (float4*)(fbase + 9600000);
    const float4* x4 = (const float4*)x;

    // CSR build
    k_zero <<<NBLK, 256, 0, stream>>>(deg, NN);
    k_count<<<(NE + 255) / 256, 256, 0, stream>>>(ei, deg);
    k_bsum <<<NBLK, 256, 0, stream>>>(deg, bsum);
    k_boff <<<1, 256, 0, stream>>>(bsum, boff, row_ptr);
    k_scan2<<<NBLK, 256, 0, stream>>>(deg, boff, row_ptr, cursor);
    k_fill <<<(NE + 255) / 256, 256, 0, stream>>>(ei, cursor, colv);

    int nb = (NN + TILE - 1) / TILE;  // 782

    // one gather of x, three MLPs: H0 = f0(x), tA = f1(x), out = f2(x)
    k_aggmlp3<<<nb, TPB, 0, stream>>>(x4, row_ptr, colv,
                                      W1_0, b1_0, W2_0, b2_0,
                                      W1_1, b1_1, W2_1, b2_1,
                                      W1_2, b1_2, W2_2, b2_2,
                                      H0, tA, out);

    // hop-2 tail: H1 = f1(tA)
    k_conv<<<nb, TPB, 0, stream>>>((const float4*)tA, row_ptr, colv,
                                   W1_1, b1_1, W2_1, b2_1, H1);

    // hop-3 tail: tA = f2(out); H2 = f2(tA)
    k_conv<<<nb, TPB, 0, stream>>>((const float4*)out, row_ptr, colv,
                                   W1_2, b1_2, W2_2, b2_2, tA);
    k_conv<<<nb, TPB, 0, stream>>>((const float4*)tA, row_ptr, colv,
                                   W1_2, b1_2, W2_2, b2_2, H2);

    // final projection
    k_final<<<nb, TPB, 0, stream>>>((const float4*)H0, (const float4*)H1, (const float4*)H2,
                                    Wo, bo, out);
}